// Round 9
// baseline (40.488 us; speedup 1.0000x reference)
//
#include <hip/hip_runtime.h>
#include <hip/hip_bf16.h>

// Problem constants (from reference):
//   B=32, S=512, D=768, N=128, LMAX=16
// Algebraic simplification (verified R1: absmax 0.031 << 0.385):
//   agg[b,n,d] = sum_{m=0}^{len-1} embeddings[b, start+m, d].
//   W and b cancel entirely (softmax columns sum to 1, then valid-mask).
//
// R9: exactly-once reads. R6-R8 (3 schedules) all plateaued at 15.2-15.5us
// -> cache-window tuning is exhausted; binder is read-path traffic
// (~104MB L2/L3-level, re-read factor 2.17, scattered 3KB rows).
// New structure: block owns (batch, 64-row window, D-half); stages its
// 64 own rows + 15 halo rows (LMAX-1) into LDS (79 x 1.5KB = 118.5KB),
// then computes every span whose START falls in its window from LDS.
// Reads: 48MB x 79/64 = 59MB, contiguous 1.5KB chunks (h=0/h=1 blocks of
// the same window sit on the same XCD and interleave to full 3KB rows).
// Each output element written exactly once (owner = start>>6; halo covers
// window-crossing spans). No atomics, no init, deterministic.
// Plain stores only (R4 lesson: nt stores raced harness poison lines).

constexpr int B_    = 32;
constexpr int S_    = 512;
constexpr int D_    = 768;
constexpr int N_    = 128;
constexpr int LMAX_ = 16;

constexpr int ROWS_OWN = 64;                    // rows owned per block
constexpr int HALO     = LMAX_ - 1;             // 15
constexpr int ROWS_STG = ROWS_OWN + HALO;       // 79 rows staged
constexpr int NSEG     = S_ / ROWS_OWN;         // 8 windows
constexpr int HALF     = D_ / 2;                // 384 floats per D-half
constexpr int QPH      = HALF / 4;              // 96 f32x4 per half-row
constexpr int TPB      = 384;                   // 6 waves
constexpr int SLOTS    = TPB / QPH;             // 4 span slots per block

typedef float f32x4 __attribute__((ext_vector_type(4)));

__global__ __launch_bounds__(TPB) void span_sum_halo_kernel(
    const float* __restrict__ emb,     // [B,S,D]
    const int*   __restrict__ spans,   // [B,N,2] (start, inclusive end)
    float*       __restrict__ out)     // [B,N,D]
{
    __shared__ f32x4 lds[ROWS_STG][QPH];   // 79*96*16B = 118.5 KiB

    // bid = (w<<3)|xcd ; per XCD: 64 work items = 4 batches x 8 segs x 2 halves.
    // h is the LSB of w so the two D-halves of a window are bids 8 apart
    // (same XCD, dispatched near-simultaneously -> interleaved row streams).
    const int bid = blockIdx.x;            // 0..511
    const int xcd = bid & 7;
    const int w   = bid >> 3;              // 0..63
    const int b   = (xcd << 2) | (w >> 4);
    const int rst = w & 15;
    const int seg = rst >> 1;              // 0..7 : 64-row window
    const int h   = rst & 1;               // D-half

    const int t    = threadIdx.x;          // 0..383
    const int q    = t % QPH;              // f32x4 lane within half-row
    const int slot = t / QPH;              // 0..3

    const int r0 = seg * ROWS_OWN;         // first staged global row

    // ---- stage rows r0 .. r0+78 (clamped to S) for D-half h ----
    const float* base = emb + ((size_t)b * S_ + (size_t)r0) * D_ + (size_t)h * HALF;
    #pragma unroll
    for (int p = 0; p < (ROWS_STG + SLOTS - 1) / SLOTS; ++p) {   // 20 passes
        const int r = p * SLOTS + slot;                          // 0..79
        if (r < ROWS_STG && r0 + r < S_)
            lds[r][q] = *reinterpret_cast<const f32x4*>(base + (size_t)r * D_ + q * 4);
    }
    __syncthreads();

    // ---- scan this batch's 128 spans; process those starting in our window.
    // cnt is identical across all threads (uniform branches); matches are
    // round-robined over the 4 slot groups.
    int cnt = 0;
    for (int n = 0; n < N_; ++n) {
        const int sid   = b * N_ + n;
        const int start = spans[2 * sid + 0];
        if ((start >> 6) == seg) {
            if ((cnt & (SLOTS - 1)) == slot) {
                const int lm1 = spans[2 * sid + 1] - start;   // len-1, 0..15
                const int lr  = start - r0;                   // 0..63
                f32x4 acc = {0.f, 0.f, 0.f, 0.f};
                #pragma unroll
                for (int m = 0; m < LMAX_; ++m) {
                    const int  mm = (m <= lm1) ? m : lm1;     // lr+mm <= 78
                    const float s = (m <= lm1) ? 1.0f : 0.0f;
                    acc += s * lds[lr + mm][q];
                }
                *(reinterpret_cast<f32x4*>(out + (size_t)sid * D_ + (size_t)h * HALF) + q) = acc;
            }
            ++cnt;
        }
    }
}

extern "C" void kernel_launch(void* const* d_in, const int* in_sizes, int n_in,
                              void* d_out, int out_size, void* d_ws, size_t ws_size,
                              hipStream_t stream) {
    const float* emb   = (const float*)d_in[0];   // [B,S,D] fp32
    // d_in[1] = W, d_in[2] = b : unused (cancel algebraically)
    const int*   spans = (const int*)d_in[3];     // [B,N,2] int32
    float*       out   = (float*)d_out;           // [B,N,D] fp32

    dim3 grid(B_ * NSEG * 2);     // 512 blocks (118.5KB LDS -> 1 resident/CU)
    dim3 block(TPB);              // 384 threads = 6 waves
    span_sum_halo_kernel<<<grid, block, 0, stream>>>(emb, spans, out);
}

// Round 10
// 15.142 us; speedup vs baseline: 2.6739x; 2.6739x over previous
//
#include <hip/hip_runtime.h>
#include <hip/hip_bf16.h>

// Problem constants (from reference):
//   B=32, S=512, D=768, N=128, LMAX=16
// Algebraic simplification (verified R1: absmax 0.031 << 0.385):
//   softmax over l sums to 1 per column m (row 0 always valid since len>=1),
//   then columns are masked by valid[m], so
//   agg[b,n,d] = sum_{m=0}^{len-1} embeddings[b, start+m, d].
//   W and b cancel entirely.
//
// R10 = revert to R7 (best: 15.19us). Session evidence:
//  - R6/R7/R8: four schedules (scattered, XCD-affine, fat-block, persistent
//    1-blk/CU with guaranteed 1.5MB L2 window) all 15.2-15.5us -> plateau is
//    schedule-invariant; L2-hit conversion is not the lever.
//  - R9 counters: FETCH 25MB, hbm 856GB/s (10% peak) -> embeddings are
//    L3-resident across replays; HBM never the binder. LDS read-once lost
//    2.6x to stage/compute serialization at 1 blk/CU.
//  - Binder: ~60-117MB mixed read+write through the L3/fabric path at the
//    measured ~6.3-6.9 TB/s service ceiling => ~15us floor for this op.
// Plain stores only (R4 lesson: nt stores raced harness poison lines).

constexpr int B_    = 32;
constexpr int S_    = 512;
constexpr int D_    = 768;
constexpr int N_    = 128;
constexpr int LMAX_ = 16;
constexpr int SPB   = 4;            // spans per block
constexpr int TPS   = D_ / 4;       // 192 threads per span

typedef float f32x4 __attribute__((ext_vector_type(4)));

__global__ __launch_bounds__(SPB * TPS) void span_sum_kernel(
    const float* __restrict__ emb,     // [B,S,D]
    const int*   __restrict__ spans,   // [B,N,2] (start, inclusive end)
    float*       __restrict__ out)     // [B,N,D]
{
    // XCD-affinity remap: xcd = bid&7, k = bid>>3 (0..127);
    // batch = 4*xcd + k/32 (sequential per XCD), span group = k%32.
    const int bid = blockIdx.x;        // 0..1023
    const int x   = bid & 7;
    const int k   = bid >> 3;
    const int b   = (x << 2) | (k >> 5);
    const int g   = k & 31;

    const int t    = threadIdx.x;      // 0..767
    const int sp   = t / TPS;          // 0..3 (wave-aligned: 192 = 3 waves)
    const int lane = t - sp * TPS;     // 0..191 : f32x4 lane across D

    const int n   = (g << 2) | sp;
    const int sid = b * N_ + n;

    const int start = spans[2 * sid + 0];
    const int lm1   = spans[2 * sid + 1] - start;   // len-1, in [0,15]

    const f32x4* __restrict__ row =
        reinterpret_cast<const f32x4*>(emb + (size_t)b * S_ * D_ + (size_t)start * D_) + lane;

    f32x4 acc = {0.f, 0.f, 0.f, 0.f};
    #pragma unroll
    for (int gq = 0; gq < LMAX_ / 4; ++gq) {
        if ((gq << 2) <= lm1) {                      // wave-uniform branch
            #pragma unroll
            for (int m4 = 0; m4 < 4; ++m4) {
                const int  m  = (gq << 2) | m4;
                const int  mm = (m <= lm1) ? m : lm1;     // clamp: dup = L1 hit
                const float s = (m <= lm1) ? 1.0f : 0.0f; // mask
                acc += s * row[(size_t)mm * (D_ / 4)];
            }
        }
    }

    *(reinterpret_cast<f32x4*>(out + (size_t)sid * D_) + lane) = acc;
}

extern "C" void kernel_launch(void* const* d_in, const int* in_sizes, int n_in,
                              void* d_out, int out_size, void* d_ws, size_t ws_size,
                              hipStream_t stream) {
    const float* emb   = (const float*)d_in[0];   // [B,S,D] fp32
    // d_in[1] = W, d_in[2] = b : unused (cancel algebraically)
    const int*   spans = (const int*)d_in[3];     // [B,N,2] int32
    float*       out   = (float*)d_out;           // [B,N,D] fp32

    dim3 grid(B_ * N_ / SPB);     // 1024 blocks
    dim3 block(SPB * TPS);        // 768 threads = 12 waves
    span_sum_kernel<<<grid, block, 0, stream>>>(emb, spans, out);
}